// Round 14
// baseline (68.259 us; speedup 1.0000x reference)
//
#include <hip/hip_runtime.h>
#include <hip/hip_bf16.h>

#define B_ 4
#define T_ 4096
#define C_ 1024
#define D_ 128

typedef __attribute__((ext_vector_type(8))) short short8;
typedef __attribute__((ext_vector_type(4))) float f32x4;
typedef __attribute__((ext_vector_type(16))) float f32x16;
typedef __attribute__((ext_vector_type(4))) unsigned short ushort4v;

static __device__ __forceinline__ unsigned short f2b(float f) {
    __hip_bfloat16 h = __float2bfloat16(f);
    return __builtin_bit_cast(unsigned short, h);
}
static __device__ __forceinline__ float b2f(unsigned short u) {
    return __builtin_bit_cast(float, (unsigned int)u << 16);
}

static __device__ __forceinline__ float exp2fast(float x) {
#if __has_builtin(__builtin_amdgcn_exp2f)
    return __builtin_amdgcn_exp2f(x);
#else
    return exp2f(x);
#endif
}

static __device__ __forceinline__ unsigned int pkbf(float lo, float hi) {
    return (unsigned int)f2b(lo) | ((unsigned int)f2b(hi) << 16);
}

// ---------------------------------------------------------------------------
// Kernel 0: W -> bf16 (Q|K|V rows concatenated: [384][1024])
// ---------------------------------------------------------------------------
__global__ __launch_bounds__(256) void wcvt(
    const float* __restrict__ Wq, const float* __restrict__ Wk,
    const float* __restrict__ Wv, unsigned short* __restrict__ Wb)
{
    int idx = (blockIdx.x * 256 + threadIdx.x) * 8;
    const float* src = (idx < 131072) ? (Wq + idx)
                     : (idx < 262144) ? (Wk + idx - 131072)
                                      : (Wv + idx - 262144);
    float4 a = *(const float4*)src;
    float4 c = *(const float4*)(src + 4);
    short8 o = { (short)f2b(a.x), (short)f2b(a.y), (short)f2b(a.z), (short)f2b(a.w),
                 (short)f2b(c.x), (short)f2b(c.y), (short)f2b(c.z), (short)f2b(c.w) };
    *(short8*)(Wb + idx) = o;
}

// ---------------------------------------------------------------------------
// Kernel A: fused QKV projection. 512 blocks x 512 thr (8 waves, each 32x48).
// Tile 32m x 384n, BK=64. LDS = A 4KB + B 48KB = 52KB -> with grid 512 that's
// 2 blocks/CU (R13 lesson: 56KB LDS was fine but grid 256 = 1 block/CU, so
// the TLP never existed -> all pipes idle at 43us). Next tile prefetched
// into registers; two-barrier k-step; co-resident block covers the bubble.
// XOR-swizzled LDS (conflict-free b128). Epilogue layouts:
//   Q : row-major [t][d], scaled by 1/sqrt(128)*log2(e)
//   Kp: QK^T A-frag panels  Kp[t/32][d/16][lane][8]
//   Vq: PV   B-frag panels  Vq[t/32][(tl>>4)*4+d/32][lane][8]
// ---------------------------------------------------------------------------
__global__ __launch_bounds__(512, 2) void qkv_gemm(
    const float* __restrict__ x, const unsigned short* __restrict__ Wb,
    unsigned short* __restrict__ qkv)
{
    __shared__ unsigned short Al[32][64];
    __shared__ unsigned short Bl[384][64];
    const int tid = threadIdx.x, lane = tid & 63, w = tid >> 6;
    const int l16 = lane & 15, lg = lane >> 4;
    const int wc = w * 48;              // 8 waves x 48 cols
    const int m0 = blockIdx.x << 5;     // 32-row tile

    const int arow = tid >> 4, ac4 = (tid & 15) << 2;   // 1 float4 / thread
    const float* aptr = x + (size_t)(m0 + arow) * C_ + ac4;
    int brow[6], bc[6];
    #pragma unroll
    for (int i = 0; i < 6; i++) { int cl = tid + (i << 9); brow[i] = cl >> 3; bc[i] = cl & 7; }

    f32x4 acc[2][3] = {};
    float4 ra; short8 rbv[6];

    // prologue: stage k-step 0
    ra = *(const float4*)(aptr);
    #pragma unroll
    for (int i = 0; i < 6; i++) rbv[i] = *(const short8*)(Wb + (size_t)brow[i] * C_ + (bc[i] << 3));
    {
        ushort4v ha = { f2b(ra.x), f2b(ra.y), f2b(ra.z), f2b(ra.w) };
        *(ushort4v*)(&Al[arow][(((ac4 >> 3) ^ (arow & 7)) << 3) | (ac4 & 4)]) = ha;
        #pragma unroll
        for (int i = 0; i < 6; i++)
            *(short8*)(&Bl[brow[i]][(bc[i] ^ (brow[i] & 7)) << 3]) = rbv[i];
    }
    __syncthreads();

    for (int ks = 0; ks < 16; ks++) {
        if (ks < 15) {       // prefetch next tile into registers
            const int k0 = (ks + 1) << 6;
            ra = *(const float4*)(aptr + k0);
            #pragma unroll
            for (int i = 0; i < 6; i++)
                rbv[i] = *(const short8*)(Wb + (size_t)brow[i] * C_ + k0 + (bc[i] << 3));
        }
        short8 af[2][2], bf[3][2];
        #pragma unroll
        for (int mf = 0; mf < 2; mf++) {
            int row = (mf << 4) + l16;
            #pragma unroll
            for (int kf = 0; kf < 2; kf++)
                af[mf][kf] = *(const short8*)(&Al[row][((((kf << 2) + lg) ^ (row & 7)) << 3)]);
        }
        #pragma unroll
        for (int nf = 0; nf < 3; nf++) {
            int row = wc + (nf << 4) + l16;
            #pragma unroll
            for (int kf = 0; kf < 2; kf++)
                bf[nf][kf] = *(const short8*)(&Bl[row][((((kf << 2) + lg) ^ (row & 7)) << 3)]);
        }
        #pragma unroll
        for (int kf = 0; kf < 2; kf++)
            #pragma unroll
            for (int mf = 0; mf < 2; mf++)
                #pragma unroll
                for (int nf = 0; nf < 3; nf++)
                    acc[mf][nf] = __builtin_amdgcn_mfma_f32_16x16x32_bf16(af[mf][kf], bf[nf][kf], acc[mf][nf], 0, 0, 0);
        if (ks < 15) {
            __syncthreads();   // all waves done reading Al/Bl
            ushort4v ha = { f2b(ra.x), f2b(ra.y), f2b(ra.z), f2b(ra.w) };
            *(ushort4v*)(&Al[arow][(((ac4 >> 3) ^ (arow & 7)) << 3) | (ac4 & 4)]) = ha;
            #pragma unroll
            for (int i = 0; i < 6; i++)
                *(short8*)(&Bl[brow[i]][(bc[i] ^ (brow[i] & 7)) << 3]) = rbv[i];
            __syncthreads();   // writes visible
        }
    }

    const float SQ = 0.08838834764831845f * 1.4426950408889634f;  // 1/sqrt(128)*log2e
    unsigned short* Qo = qkv;
    unsigned short* Kp = qkv + (size_t)B_ * T_ * D_;
    unsigned short* Vq = qkv + 2 * (size_t)B_ * T_ * D_;
    #pragma unroll
    for (int mf = 0; mf < 2; mf++) {
        #pragma unroll
        for (int nf = 0; nf < 3; nf++) {
            int cg  = wc + (nf << 4);
            int mat = cg >> 7;
            int cc  = (cg & 127) + l16;
            #pragma unroll
            for (int r = 0; r < 4; r++) {
                int row = m0 + (mf << 4) + (lg << 2) + r;
                float v = acc[mf][nf][r];
                int t = row & (T_ - 1), bb = row >> 12;
                size_t bo = (size_t)bb << 19;
                if (mat == 0) {
                    Qo[(size_t)row * D_ + cc] = f2b(v * SQ);
                } else if (mat == 1) {
                    Kp[bo + ((size_t)(t >> 5) << 12) + ((size_t)(cc >> 4) << 9)
                       + (((cc >> 3) & 1) << 8) + ((t & 31) << 3) + (cc & 7)] = f2b(v);
                } else {
                    int tl = t & 31;
                    Vq[bo + ((size_t)(t >> 5) << 12)
                       + ((size_t)(((tl >> 4) << 2) + (cc >> 5)) << 9)
                       + ((((tl >> 3) & 1) << 8) + ((cc & 31) << 3)) + (tl & 7)] = f2b(v);
                }
            }
        }
    }
}

// ---------------------------------------------------------------------------
// Kernel B: causal flash attention. 512 blocks x 512 thr.
// One 32-row q-tile per block; blocks beta and beta+256 take complementary
// tiles {p, 127-p} -> co-resident pairs have constant total work.
// bf16 RAW-partial merge scratch: LDS 66KB -> 2 blocks/CU; natural VGPR
// ~128 -> 4 waves/SIMD. K-loop: 8-way interleaved key split, zero barriers,
// dense 1KB panel loads, in-register softmax (tree + shfl), defer-max,
// in-reg P->A-frag pack (cndmask+shfl). Reader-side merge weighting.
// ---------------------------------------------------------------------------
__global__ __launch_bounds__(512, 2) void attn_fwd(
    const unsigned short* __restrict__ Q,
    const unsigned short* __restrict__ Kp,
    const unsigned short* __restrict__ Vq,
    float* __restrict__ out)
{
    __shared__ unsigned short scb[8][32][128];   // bf16 RAW partials (64KB)
    __shared__ float mlS[8][32][2];

    const int beta0 = blockIdx.x;
    const int sel   = beta0 >> 8;          // 0: tile p, 1: tile 127-p
    const int beta  = beta0 & 255;
    const int xcd   = beta & 7;
    const int b     = xcd >> 1;
    const int pp    = ((beta >> 3) << 1) | (xcd & 1);   // 0..63
    const int it    = sel ? (127 - pp) : pp;
    const int qb    = it << 5;

    const int tid = threadIdx.x, lane = tid & 63, w = tid >> 6;
    const int l32 = lane & 31, lh = lane >> 5;
    const bool lo = (lh == 0);
    const size_t base = (size_t)b * T_ * D_;
    const unsigned short* Kpb = Kp + ((size_t)b << 19);
    const unsigned short* Vqb = Vq + ((size_t)b << 19);

    // Q B-fragments (scale+log2e folded): qf[ds] = Q[qb+l32][16ds+8lh+j]
    short8 qf[8];
    {
        const unsigned short* qp = Q + base + (size_t)(qb + l32) * D_ + (lh << 3);
        #pragma unroll
        for (int ds = 0; ds < 8; ds++) qf[ds] = *(const short8*)(qp + (ds << 4));
    }
    f32x16 accO[4] = {};
    float m_s = -1e30f, l_s = 0.f;

    short8 ka[8], vb[8];

    auto loadKA = [&](int cc) {
        const unsigned short* kp = Kpb + ((size_t)cc << 12) + (lane << 3);
        #pragma unroll
        for (int i = 0; i < 8; i++) ka[i] = *(const short8*)(kp + (i << 9));
    };
    auto loadVB = [&](int cc) {
        const unsigned short* vp = Vqb + ((size_t)cc << 12) + (lane << 3);
        #pragma unroll
        for (int i = 0; i < 8; i++) vb[i] = *(const short8*)(vp + (i << 9));
    };
    auto qkt = [&]() -> f32x16 {
        f32x16 s = {};
        #pragma unroll
        for (int ds = 0; ds < 8; ds++)
            s = __builtin_amdgcn_mfma_f32_32x32x16_bf16(ka[ds], qf[ds], s, 0, 0, 0);
        return s;
    };
    // softmax + pack + PV for chunk cc whose scores are in s2
    auto process = [&](f32x16 &s2, int cc) {
        if (cc == it) {   // diagonal causal mask
            #pragma unroll
            for (int r = 0; r < 16; r++) {
                int kl = (r & 3) + ((r >> 2) << 3) + (lh << 2);
                if (kl > l32) s2[r] = -1e30f;
            }
        }
        // tree max (depth 4) + cross-half shfl
        float t0 = fmaxf(s2[0], s2[1]),   t1 = fmaxf(s2[2], s2[3]);
        float t2 = fmaxf(s2[4], s2[5]),   t3 = fmaxf(s2[6], s2[7]);
        float t4 = fmaxf(s2[8], s2[9]),   t5 = fmaxf(s2[10], s2[11]);
        float t6 = fmaxf(s2[12], s2[13]), t7 = fmaxf(s2[14], s2[15]);
        t0 = fmaxf(t0, t1); t2 = fmaxf(t2, t3); t4 = fmaxf(t4, t5); t6 = fmaxf(t6, t7);
        float mx = fmaxf(fmaxf(t0, t2), fmaxf(t4, t6));
        mx = fmaxf(mx, __shfl_xor(mx, 32));
        // defer-max rescale (rare)
        if (!__all(mx <= m_s + 8.0f)) {
            float mnew = fmaxf(m_s, mx);
            float al = exp2fast(m_s - mnew);
            m_s = mnew; l_s *= al;
            #pragma unroll
            for (int r = 0; r < 16; r++) {
                float av = __shfl(al, (r & 3) + ((r >> 2) << 3) + (lh << 2));
                accO[0][r] *= av; accO[1][r] *= av; accO[2][r] *= av; accO[3][r] *= av;
            }
        }
        #pragma unroll
        for (int r = 0; r < 16; r++) s2[r] = exp2fast(s2[r] - m_s);
        // tree sum + cross-half shfl
        float u0 = s2[0] + s2[1],   u1 = s2[2] + s2[3];
        float u2 = s2[4] + s2[5],   u3 = s2[6] + s2[7];
        float u4 = s2[8] + s2[9],   u5 = s2[10] + s2[11];
        float u6 = s2[12] + s2[13], u7 = s2[14] + s2[15];
        u0 += u1; u2 += u3; u4 += u5; u6 += u7;
        float rs = (u0 + u2) + (u4 + u6);
        rs += __shfl_xor(rs, 32);
        l_s += rs;
        // pack P -> PV A-frags (verified cndmask + shfl transpose)
        unsigned int A0 = pkbf(s2[0],  s2[1]),  B0 = pkbf(s2[2],  s2[3]);
        unsigned int C0 = pkbf(s2[4],  s2[5]),  D0 = pkbf(s2[6],  s2[7]);
        unsigned int A1 = pkbf(s2[8],  s2[9]),  B1 = pkbf(s2[10], s2[11]);
        unsigned int C1 = pkbf(s2[12], s2[13]), D1 = pkbf(s2[14], s2[15]);
        union { unsigned int u[4]; short8 s; } f0, f1;
        {
            unsigned int u0v = lo ? C0 : A0, v0v = lo ? D0 : B0;
            unsigned int su = (unsigned int)__shfl_xor((int)u0v, 32);
            unsigned int sv = (unsigned int)__shfl_xor((int)v0v, 32);
            f0.u[0] = lo ? A0 : su; f0.u[1] = lo ? B0 : sv;
            f0.u[2] = lo ? su : C0; f0.u[3] = lo ? sv : D0;
        }
        {
            unsigned int u1v = lo ? C1 : A1, v1v = lo ? D1 : B1;
            unsigned int su = (unsigned int)__shfl_xor((int)u1v, 32);
            unsigned int sv = (unsigned int)__shfl_xor((int)v1v, 32);
            f1.u[0] = lo ? A1 : su; f1.u[1] = lo ? B1 : sv;
            f1.u[2] = lo ? su : C1; f1.u[3] = lo ? sv : D1;
        }
        // O += P V
        #pragma unroll
        for (int db = 0; db < 4; db++)
            accO[db] = __builtin_amdgcn_mfma_f32_32x32x16_bf16(f0.s, vb[db], accO[db], 0, 0, 0);
        #pragma unroll
        for (int db = 0; db < 4; db++)
            accO[db] = __builtin_amdgcn_mfma_f32_32x32x16_bf16(f1.s, vb[4 + db], accO[db], 0, 0, 0);
    };

    int c = w;
    if (c <= it) {
        loadKA(c);
        loadVB(c);
        #pragma unroll 1
        while (true) {
            f32x16 s2 = qkt();
            bool hn = (c + 8 <= it);
            if (hn) loadKA(c + 8);      // ka free after QK^T
            process(s2, c);
            if (hn) loadVB(c + 8);      // vb free after PV
            c += 8;
            if (!hn) break;
        }
    }

    // ---- 8-way merge: RAW bf16 partials; all per-q weights in the reader ----
    if (lane < 32) { mlS[w][lane][0] = m_s; mlS[w][lane][1] = l_s; }
    #pragma unroll
    for (int r = 0; r < 16; r++) {
        int q = (r & 3) + ((r >> 2) << 3) + (lh << 2);
        #pragma unroll
        for (int db = 0; db < 4; db++)
            scb[w][q][(db << 5) + l32] = f2b(accO[db][r]);
    }
    __syncthreads();
    {
        const int q = tid >> 4, dc = (tid & 15) << 3;
        float fw[8], mst = -1e30f, lst = 0.f;
        #pragma unroll
        for (int w2 = 0; w2 < 8; w2++) mst = fmaxf(mst, mlS[w2][q][0]);
        #pragma unroll
        for (int w2 = 0; w2 < 8; w2++) {
            fw[w2] = exp2fast(mlS[w2][q][0] - mst);
            lst += fw[w2] * mlS[w2][q][1];
        }
        float inv = 1.0f / lst;
        float o[8] = {};
        #pragma unroll
        for (int w2 = 0; w2 < 8; w2++) {
            short8 sv = *(const short8*)(&scb[w2][q][dc]);
            #pragma unroll
            for (int j = 0; j < 8; j++)
                o[j] += fw[w2] * b2f((unsigned short)sv[j]);
        }
        float* op = out + base + (size_t)(qb + q) * D_ + dc;
        f32x4 o0 = { o[0], o[1], o[2], o[3] };
        f32x4 o1 = { o[4], o[5], o[6], o[7] };
        *(f32x4*)op = o0 * inv;
        *(f32x4*)(op + 4) = o1 * inv;
    }
}

extern "C" void kernel_launch(void* const* d_in, const int* in_sizes, int n_in,
                              void* d_out, int out_size, void* d_ws, size_t ws_size,
                              hipStream_t stream) {
    (void)in_sizes; (void)n_in; (void)out_size; (void)ws_size;
    const float* x  = (const float*)d_in[0];
    const float* Wq = (const float*)d_in[1];
    const float* Wk = (const float*)d_in[2];
    const float* Wv = (const float*)d_in[3];

    unsigned short* qkv = (unsigned short*)d_ws;     // Q | Kp | Vq, bf16, 4MB each
    unsigned short* Wb  = (unsigned short*)d_out;    // temp bf16 W (overwritten by attn)

    wcvt<<<dim3(192), 256, 0, stream>>>(Wq, Wk, Wv, Wb);
    qkv_gemm<<<dim3(512), 512, 0, stream>>>(x, Wb, qkv);

    const unsigned short* Qw = qkv;
    const unsigned short* Kw = qkv + (size_t)B_ * T_ * D_;
    const unsigned short* Vw = qkv + 2 * (size_t)B_ * T_ * D_;
    attn_fwd<<<dim3(512), 512, 0, stream>>>(Qw, Kw, Vw, (float*)d_out);
}

// Round 15
// 65.112 us; speedup vs baseline: 1.0483x; 1.0483x over previous
//
#include <hip/hip_runtime.h>
#include <hip/hip_bf16.h>

#define B_ 4
#define T_ 4096
#define C_ 1024
#define D_ 128

typedef __attribute__((ext_vector_type(8))) short short8;
typedef __attribute__((ext_vector_type(4))) float f32x4;
typedef __attribute__((ext_vector_type(16))) float f32x16;
typedef __attribute__((ext_vector_type(4))) unsigned short ushort4v;

static __device__ __forceinline__ unsigned short f2b(float f) {
    __hip_bfloat16 h = __float2bfloat16(f);
    return __builtin_bit_cast(unsigned short, h);
}
static __device__ __forceinline__ float b2f(unsigned short u) {
    return __builtin_bit_cast(float, (unsigned int)u << 16);
}

static __device__ __forceinline__ float exp2fast(float x) {
#if __has_builtin(__builtin_amdgcn_exp2f)
    return __builtin_amdgcn_exp2f(x);
#else
    return exp2f(x);
#endif
}

static __device__ __forceinline__ unsigned int pkbf(float lo, float hi) {
    return (unsigned int)f2b(lo) | ((unsigned int)f2b(hi) << 16);
}

// ---------------------------------------------------------------------------
// Kernel 0: W -> bf16 B-FRAGMENT PANELS.
// Wp frag (n16, ks, kf) is a contiguous 1KB wave-load: lane (lg<<4|l16),
// j in 0..7 holds W[n16*16+l16][ks*64+kf*32+lg*8+j].
// (R14 post-mortem: GEMM was LDS-pipe-bound; B staged through LDS cost
//  12 of 17 LDS ops per wave per k-step. Panels let gemm read B direct
//  from L2 with zero LDS involvement.)
// ---------------------------------------------------------------------------
__global__ __launch_bounds__(256) void wcvt(
    const float* __restrict__ Wq, const float* __restrict__ Wk,
    const float* __restrict__ Wv, unsigned short* __restrict__ Wp)
{
    int t8 = blockIdx.x * 256 + threadIdx.x;   // 49152 threads, 8 elems each
    int n  = t8 >> 7;                          // 0..383
    int c0 = (t8 & 127) << 3;                  // 0..1016
    const float* src = (n < 128) ? (Wq + (size_t)n * C_ + c0)
                     : (n < 256) ? (Wk + (size_t)(n - 128) * C_ + c0)
                                 : (Wv + (size_t)(n - 256) * C_ + c0);
    float4 a = *(const float4*)src;
    float4 c = *(const float4*)(src + 4);
    short8 o = { (short)f2b(a.x), (short)f2b(a.y), (short)f2b(a.z), (short)f2b(a.w),
                 (short)f2b(c.x), (short)f2b(c.y), (short)f2b(c.z), (short)f2b(c.w) };
    int n16 = n >> 4, l16 = n & 15;
    int ks = c0 >> 6, kf = (c0 >> 5) & 1, lg = (c0 >> 3) & 3;
    int lane = (lg << 4) | l16;
    *(short8*)(Wp + (((size_t)(n16 * 32 + ks * 2 + kf) << 9) + (lane << 3))) = o;
}

// ---------------------------------------------------------------------------
// Kernel A: fused QKV projection. 512 blocks x 512 thr (8 waves, each 32x48).
// Tile 32m x 384n, BK=64. B-frags read DIRECT from L2-resident Wp panels
// (no B LDS at all). A (x) staged in 8KB double-buffered LDS with DEPTH-2
// register prefetch (x(k+3) issued at step k, consumed at k+2: ~2 k-steps
// of HBM latency coverage). Single barrier per k-step. Fully unrolled
// (static ping-pong regs). Epilogue layouts:
//   Q : row-major [t][d], scaled by 1/sqrt(128)*log2(e)
//   Kp: QK^T A-frag panels  Kp[t/32][d/16][lane][8]
//   Vq: PV   B-frag panels  Vq[t/32][(tl>>4)*4+d/32][lane][8]
// ---------------------------------------------------------------------------
__global__ __launch_bounds__(512, 2) void qkv_gemm(
    const float* __restrict__ x, const unsigned short* __restrict__ Wp,
    unsigned short* __restrict__ qkv)
{
    __shared__ unsigned short Al[2][32][64];
    const int tid = threadIdx.x, lane = tid & 63, w = tid >> 6;
    const int l16 = lane & 15, lg = lane >> 4;
    const int wc = w * 48;              // 8 waves x 48 cols
    const int m0 = blockIdx.x << 5;     // 32-row tile

    const int arow = tid >> 4, ac4 = (tid & 15) << 2;   // 1 float4 / thread
    const float* aptr = x + (size_t)(m0 + arow) * C_ + ac4;

    auto writeA = [&](int buf, float4 v) {
        ushort4v ha = { f2b(v.x), f2b(v.y), f2b(v.z), f2b(v.w) };
        *(ushort4v*)(&Al[buf][arow][(((ac4 >> 3) ^ (arow & 7)) << 3) | (ac4 & 4)]) = ha;
    };

    f32x4 acc[2][3] = {};

    // prologue: stage x(0); prefetch x(1), x(2) into ping-pong regs
    {
        float4 r0 = *(const float4*)(aptr);
        writeA(0, r0);
    }
    float4 rA = *(const float4*)(aptr + 64);    // x(1)  (odd steps)
    float4 rB = *(const float4*)(aptr + 128);   // x(2)  (even steps)
    __syncthreads();

    const unsigned short* wpw = Wp + ((size_t)(w * 3) << 14) + (lane << 3);

    #pragma unroll
    for (int ks = 0; ks < 16; ks++) {
        const int cur = ks & 1;
        // B-frags direct from L2 panels (6 x 1KB wave-loads)
        short8 bf[3][2];
        #pragma unroll
        for (int nf = 0; nf < 3; nf++)
            #pragma unroll
            for (int kf = 0; kf < 2; kf++)
                bf[nf][kf] = *(const short8*)(wpw + ((size_t)nf << 14) + ((ks * 2 + kf) << 9));
        // A-frags from LDS
        short8 af[2][2];
        #pragma unroll
        for (int mf = 0; mf < 2; mf++) {
            int row = (mf << 4) + l16;
            #pragma unroll
            for (int kf = 0; kf < 2; kf++)
                af[mf][kf] = *(const short8*)(&Al[cur][row][((((kf << 2) + lg) ^ (row & 7)) << 3)]);
        }
        #pragma unroll
        for (int kf = 0; kf < 2; kf++)
            #pragma unroll
            for (int mf = 0; mf < 2; mf++)
                #pragma unroll
                for (int nf = 0; nf < 3; nf++)
                    acc[mf][nf] = __builtin_amdgcn_mfma_f32_16x16x32_bf16(af[mf][kf], bf[nf][kf], acc[mf][nf], 0, 0, 0);
        if (ks < 15) {
            // write x(ks+1) into the other buffer (load issued >=2 steps ago)
            writeA(cur ^ 1, ((ks + 1) & 1) ? rA : rB);
            if (ks + 3 < 16) {           // refill the freed ping-pong reg
                float4 nv = *(const float4*)(aptr + (ks + 3) * 64);
                if ((ks + 3) & 1) rA = nv; else rB = nv;
            }
        }
        __syncthreads();
    }

    const float SQ = 0.08838834764831845f * 1.4426950408889634f;  // 1/sqrt(128)*log2e
    unsigned short* Qo = qkv;
    unsigned short* Kp = qkv + (size_t)B_ * T_ * D_;
    unsigned short* Vq = qkv + 2 * (size_t)B_ * T_ * D_;
    #pragma unroll
    for (int mf = 0; mf < 2; mf++) {
        #pragma unroll
        for (int nf = 0; nf < 3; nf++) {
            int cg  = wc + (nf << 4);
            int mat = cg >> 7;
            int cc  = (cg & 127) + l16;
            #pragma unroll
            for (int r = 0; r < 4; r++) {
                int row = m0 + (mf << 4) + (lg << 2) + r;
                float v = acc[mf][nf][r];
                int t = row & (T_ - 1), bb = row >> 12;
                size_t bo = (size_t)bb << 19;
                if (mat == 0) {
                    Qo[(size_t)row * D_ + cc] = f2b(v * SQ);
                } else if (mat == 1) {
                    Kp[bo + ((size_t)(t >> 5) << 12) + ((size_t)(cc >> 4) << 9)
                       + (((cc >> 3) & 1) << 8) + ((t & 31) << 3) + (cc & 7)] = f2b(v);
                } else {
                    int tl = t & 31;
                    Vq[bo + ((size_t)(t >> 5) << 12)
                       + ((size_t)(((tl >> 4) << 2) + (cc >> 5)) << 9)
                       + ((((tl >> 3) & 1) << 8) + ((cc & 31) << 3)) + (tl & 7)] = f2b(v);
                }
            }
        }
    }
}

// ---------------------------------------------------------------------------
// Kernel B: causal flash attention. 512 blocks x 512 thr. (unchanged)
// One 32-row q-tile per block; blocks beta and beta+256 take complementary
// tiles {p, 127-p}. bf16 RAW-partial merge scratch: LDS 66KB -> 2 blocks/CU;
// natural VGPR ~128 -> 4 waves/SIMD. K-loop: 8-way interleaved key split,
// zero barriers, dense 1KB panel loads, in-register softmax (tree + shfl),
// defer-max, in-reg P->A-frag pack (cndmask+shfl). Reader-side merge.
// ---------------------------------------------------------------------------
__global__ __launch_bounds__(512, 2) void attn_fwd(
    const unsigned short* __restrict__ Q,
    const unsigned short* __restrict__ Kp,
    const unsigned short* __restrict__ Vq,
    float* __restrict__ out)
{
    __shared__ unsigned short scb[8][32][128];   // bf16 RAW partials (64KB)
    __shared__ float mlS[8][32][2];

    const int beta0 = blockIdx.x;
    const int sel   = beta0 >> 8;          // 0: tile p, 1: tile 127-p
    const int beta  = beta0 & 255;
    const int xcd   = beta & 7;
    const int b     = xcd >> 1;
    const int pp    = ((beta >> 3) << 1) | (xcd & 1);   // 0..63
    const int it    = sel ? (127 - pp) : pp;
    const int qb    = it << 5;

    const int tid = threadIdx.x, lane = tid & 63, w = tid >> 6;
    const int l32 = lane & 31, lh = lane >> 5;
    const bool lo = (lh == 0);
    const size_t base = (size_t)b * T_ * D_;
    const unsigned short* Kpb = Kp + ((size_t)b << 19);
    const unsigned short* Vqb = Vq + ((size_t)b << 19);

    // Q B-fragments (scale+log2e folded): qf[ds] = Q[qb+l32][16ds+8lh+j]
    short8 qf[8];
    {
        const unsigned short* qp = Q + base + (size_t)(qb + l32) * D_ + (lh << 3);
        #pragma unroll
        for (int ds = 0; ds < 8; ds++) qf[ds] = *(const short8*)(qp + (ds << 4));
    }
    f32x16 accO[4] = {};
    float m_s = -1e30f, l_s = 0.f;

    short8 ka[8], vb[8];

    auto loadKA = [&](int cc) {
        const unsigned short* kp = Kpb + ((size_t)cc << 12) + (lane << 3);
        #pragma unroll
        for (int i = 0; i < 8; i++) ka[i] = *(const short8*)(kp + (i << 9));
    };
    auto loadVB = [&](int cc) {
        const unsigned short* vp = Vqb + ((size_t)cc << 12) + (lane << 3);
        #pragma unroll
        for (int i = 0; i < 8; i++) vb[i] = *(const short8*)(vp + (i << 9));
    };
    auto qkt = [&]() -> f32x16 {
        f32x16 s = {};
        #pragma unroll
        for (int ds = 0; ds < 8; ds++)
            s = __builtin_amdgcn_mfma_f32_32x32x16_bf16(ka[ds], qf[ds], s, 0, 0, 0);
        return s;
    };
    // softmax + pack + PV for chunk cc whose scores are in s2
    auto process = [&](f32x16 &s2, int cc) {
        if (cc == it) {   // diagonal causal mask
            #pragma unroll
            for (int r = 0; r < 16; r++) {
                int kl = (r & 3) + ((r >> 2) << 3) + (lh << 2);
                if (kl > l32) s2[r] = -1e30f;
            }
        }
        // tree max (depth 4) + cross-half shfl
        float t0 = fmaxf(s2[0], s2[1]),   t1 = fmaxf(s2[2], s2[3]);
        float t2 = fmaxf(s2[4], s2[5]),   t3 = fmaxf(s2[6], s2[7]);
        float t4 = fmaxf(s2[8], s2[9]),   t5 = fmaxf(s2[10], s2[11]);
        float t6 = fmaxf(s2[12], s2[13]), t7 = fmaxf(s2[14], s2[15]);
        t0 = fmaxf(t0, t1); t2 = fmaxf(t2, t3); t4 = fmaxf(t4, t5); t6 = fmaxf(t6, t7);
        float mx = fmaxf(fmaxf(t0, t2), fmaxf(t4, t6));
        mx = fmaxf(mx, __shfl_xor(mx, 32));
        // defer-max rescale (rare)
        if (!__all(mx <= m_s + 8.0f)) {
            float mnew = fmaxf(m_s, mx);
            float al = exp2fast(m_s - mnew);
            m_s = mnew; l_s *= al;
            #pragma unroll
            for (int r = 0; r < 16; r++) {
                float av = __shfl(al, (r & 3) + ((r >> 2) << 3) + (lh << 2));
                accO[0][r] *= av; accO[1][r] *= av; accO[2][r] *= av; accO[3][r] *= av;
            }
        }
        #pragma unroll
        for (int r = 0; r < 16; r++) s2[r] = exp2fast(s2[r] - m_s);
        // tree sum + cross-half shfl
        float u0 = s2[0] + s2[1],   u1 = s2[2] + s2[3];
        float u2 = s2[4] + s2[5],   u3 = s2[6] + s2[7];
        float u4 = s2[8] + s2[9],   u5 = s2[10] + s2[11];
        float u6 = s2[12] + s2[13], u7 = s2[14] + s2[15];
        u0 += u1; u2 += u3; u4 += u5; u6 += u7;
        float rs = (u0 + u2) + (u4 + u6);
        rs += __shfl_xor(rs, 32);
        l_s += rs;
        // pack P -> PV A-frags (verified cndmask + shfl transpose)
        unsigned int A0 = pkbf(s2[0],  s2[1]),  B0 = pkbf(s2[2],  s2[3]);
        unsigned int C0 = pkbf(s2[4],  s2[5]),  D0 = pkbf(s2[6],  s2[7]);
        unsigned int A1 = pkbf(s2[8],  s2[9]),  B1 = pkbf(s2[10], s2[11]);
        unsigned int C1 = pkbf(s2[12], s2[13]), D1 = pkbf(s2[14], s2[15]);
        union { unsigned int u[4]; short8 s; } f0, f1;
        {
            unsigned int u0v = lo ? C0 : A0, v0v = lo ? D0 : B0;
            unsigned int su = (unsigned int)__shfl_xor((int)u0v, 32);
            unsigned int sv = (unsigned int)__shfl_xor((int)v0v, 32);
            f0.u[0] = lo ? A0 : su; f0.u[1] = lo ? B0 : sv;
            f0.u[2] = lo ? su : C0; f0.u[3] = lo ? sv : D0;
        }
        {
            unsigned int u1v = lo ? C1 : A1, v1v = lo ? D1 : B1;
            unsigned int su = (unsigned int)__shfl_xor((int)u1v, 32);
            unsigned int sv = (unsigned int)__shfl_xor((int)v1v, 32);
            f1.u[0] = lo ? A1 : su; f1.u[1] = lo ? B1 : sv;
            f1.u[2] = lo ? su : C1; f1.u[3] = lo ? sv : D1;
        }
        // O += P V
        #pragma unroll
        for (int db = 0; db < 4; db++)
            accO[db] = __builtin_amdgcn_mfma_f32_32x32x16_bf16(f0.s, vb[db], accO[db], 0, 0, 0);
        #pragma unroll
        for (int db = 0; db < 4; db++)
            accO[db] = __builtin_amdgcn_mfma_f32_32x32x16_bf16(f1.s, vb[4 + db], accO[db], 0, 0, 0);
    };

    int c = w;
    if (c <= it) {
        loadKA(c);
        loadVB(c);
        #pragma unroll 1
        while (true) {
            f32x16 s2 = qkt();
            bool hn = (c + 8 <= it);
            if (hn) loadKA(c + 8);      // ka free after QK^T
            process(s2, c);
            if (hn) loadVB(c + 8);      // vb free after PV
            c += 8;
            if (!hn) break;
        }
    }

    // ---- 8-way merge: RAW bf16 partials; all per-q weights in the reader ----
    if (lane < 32) { mlS[w][lane][0] = m_s; mlS[w][lane][1] = l_s; }
    #pragma unroll
    for (int r = 0; r < 16; r++) {
        int q = (r & 3) + ((r >> 2) << 3) + (lh << 2);
        #pragma unroll
        for (int db = 0; db < 4; db++)
            scb[w][q][(db << 5) + l32] = f2b(accO[db][r]);
    }
    __syncthreads();
    {
        const int q = tid >> 4, dc = (tid & 15) << 3;
        float fw[8], mst = -1e30f, lst = 0.f;
        #pragma unroll
        for (int w2 = 0; w2 < 8; w2++) mst = fmaxf(mst, mlS[w2][q][0]);
        #pragma unroll
        for (int w2 = 0; w2 < 8; w2++) {
            fw[w2] = exp2fast(mlS[w2][q][0] - mst);
            lst += fw[w2] * mlS[w2][q][1];
        }
        float inv = 1.0f / lst;
        float o[8] = {};
        #pragma unroll
        for (int w2 = 0; w2 < 8; w2++) {
            short8 sv = *(const short8*)(&scb[w2][q][dc]);
            #pragma unroll
            for (int j = 0; j < 8; j++)
                o[j] += fw[w2] * b2f((unsigned short)sv[j]);
        }
        float* op = out + base + (size_t)(qb + q) * D_ + dc;
        f32x4 o0 = { o[0], o[1], o[2], o[3] };
        f32x4 o1 = { o[4], o[5], o[6], o[7] };
        *(f32x4*)op = o0 * inv;
        *(f32x4*)(op + 4) = o1 * inv;
    }
}

extern "C" void kernel_launch(void* const* d_in, const int* in_sizes, int n_in,
                              void* d_out, int out_size, void* d_ws, size_t ws_size,
                              hipStream_t stream) {
    (void)in_sizes; (void)n_in; (void)out_size; (void)ws_size;
    const float* x  = (const float*)d_in[0];
    const float* Wq = (const float*)d_in[1];
    const float* Wk = (const float*)d_in[2];
    const float* Wv = (const float*)d_in[3];

    unsigned short* qkv = (unsigned short*)d_ws;     // Q | Kp | Vq, bf16, 4MB each
    unsigned short* Wp  = (unsigned short*)d_out;    // temp bf16 W panels (overwritten by attn)

    wcvt<<<dim3(192), 256, 0, stream>>>(Wq, Wk, Wv, Wp);
    qkv_gemm<<<dim3(512), 512, 0, stream>>>(x, Wp, qkv);

    const unsigned short* Qw = qkv;
    const unsigned short* Kw = qkv + (size_t)B_ * T_ * D_;
    const unsigned short* Vw = qkv + 2 * (size_t)B_ * T_ * D_;
    attn_fwd<<<dim3(512), 512, 0, stream>>>(Qw, Kw, Vw, (float*)d_out);
}

// Round 16
// 65.049 us; speedup vs baseline: 1.0494x; 1.0010x over previous
//
#include <hip/hip_runtime.h>
#include <hip/hip_bf16.h>

#define B_ 4
#define T_ 4096
#define C_ 1024
#define D_ 128

typedef __attribute__((ext_vector_type(8))) short short8;
typedef __attribute__((ext_vector_type(4))) float f32x4;
typedef __attribute__((ext_vector_type(16))) float f32x16;
typedef __attribute__((ext_vector_type(4))) unsigned short ushort4v;

static __device__ __forceinline__ unsigned short f2b(float f) {
    __hip_bfloat16 h = __float2bfloat16(f);
    return __builtin_bit_cast(unsigned short, h);
}
static __device__ __forceinline__ float b2f(unsigned short u) {
    return __builtin_bit_cast(float, (unsigned int)u << 16);
}

static __device__ __forceinline__ float exp2fast(float x) {
#if __has_builtin(__builtin_amdgcn_exp2f)
    return __builtin_amdgcn_exp2f(x);
#else
    return exp2f(x);
#endif
}

static __device__ __forceinline__ unsigned int pkbf(float lo, float hi) {
    return (unsigned int)f2b(lo) | ((unsigned int)f2b(hi) << 16);
}

// ---------------------------------------------------------------------------
// Kernel 0: W -> bf16 B-FRAGMENT PANELS.
// Wp frag (n16, ks, kf) is a contiguous 1KB wave-load: lane (lg<<4|l16),
// j in 0..7 holds W[n16*16+l16][ks*64+kf*32+lg*8+j].
// ---------------------------------------------------------------------------
__global__ __launch_bounds__(256) void wcvt(
    const float* __restrict__ Wq, const float* __restrict__ Wk,
    const float* __restrict__ Wv, unsigned short* __restrict__ Wp)
{
    int t8 = blockIdx.x * 256 + threadIdx.x;   // 49152 threads, 8 elems each
    int n  = t8 >> 7;                          // 0..383
    int c0 = (t8 & 127) << 3;                  // 0..1016
    const float* src = (n < 128) ? (Wq + (size_t)n * C_ + c0)
                     : (n < 256) ? (Wk + (size_t)(n - 128) * C_ + c0)
                                 : (Wv + (size_t)(n - 256) * C_ + c0);
    float4 a = *(const float4*)src;
    float4 c = *(const float4*)(src + 4);
    short8 o = { (short)f2b(a.x), (short)f2b(a.y), (short)f2b(a.z), (short)f2b(a.w),
                 (short)f2b(c.x), (short)f2b(c.y), (short)f2b(c.z), (short)f2b(c.w) };
    int n16 = n >> 4, l16 = n & 15;
    int ks = c0 >> 6, kf = (c0 >> 5) & 1, lg = (c0 >> 3) & 3;
    int lane = (lg << 4) | l16;
    *(short8*)(Wp + (((size_t)(n16 * 32 + ks * 2 + kf) << 9) + (lane << 3))) = o;
}

// ---------------------------------------------------------------------------
// Kernel A: fused QKV projection. 512 blocks x 512 thr (8 waves, each 32x48).
// Tile 32m x 384n, BK=64. B-frags direct from L2-resident Wp panels with
// DEPTH-1 PING-PONG PREFETCH issued at the START of each k-step (R15 lesson:
// the compiler's vmcnt(0) drain before every __syncthreads forces loads to
// complete at each barrier; loads issued at step start have the whole step
// in flight -> drain is ~free; loads issued at step end pay full latency).
// x refill issued FIRST (3-step depth). A staged in 8KB dbuf LDS, one
// barrier per step. Fully unrolled (static ping-pong). Epilogue layouts:
//   Q : row-major [t][d], scaled by 1/sqrt(128)*log2(e)
//   Kp: QK^T A-frag panels  Kp[t/32][d/16][lane][8]
//   Vq: PV   B-frag panels  Vq[t/32][(tl>>4)*4+d/32][lane][8]
// ---------------------------------------------------------------------------
__global__ __launch_bounds__(512, 2) void qkv_gemm(
    const float* __restrict__ x, const unsigned short* __restrict__ Wp,
    unsigned short* __restrict__ qkv)
{
    __shared__ unsigned short Al[2][32][64];
    const int tid = threadIdx.x, lane = tid & 63, w = tid >> 6;
    const int l16 = lane & 15, lg = lane >> 4;
    const int wc = w * 48;              // 8 waves x 48 cols
    const int m0 = blockIdx.x << 5;     // 32-row tile

    const int arow = tid >> 4, ac4 = (tid & 15) << 2;   // 1 float4 / thread
    const float* aptr = x + (size_t)(m0 + arow) * C_ + ac4;

    auto writeA = [&](int buf, float4 v) {
        ushort4v ha = { f2b(v.x), f2b(v.y), f2b(v.z), f2b(v.w) };
        *(ushort4v*)(&Al[buf][arow][(((ac4 >> 3) ^ (arow & 7)) << 3) | (ac4 & 4)]) = ha;
    };

    const unsigned short* wpw = Wp + ((size_t)(w * 3) << 14) + (lane << 3);
    short8 bfA[3][2], bfB[3][2];
    auto loadB = [&](short8 (&bf)[3][2], int ks) {
        #pragma unroll
        for (int nf = 0; nf < 3; nf++)
            #pragma unroll
            for (int kf = 0; kf < 2; kf++)
                bf[nf][kf] = *(const short8*)(wpw + ((size_t)nf << 14) + ((ks * 2 + kf) << 9));
    };

    f32x4 acc[2][3] = {};

    // prologue: stage x(0) -> LDS; x(1),x(2) -> ping-pong regs; B(0) -> bfA
    writeA(0, *(const float4*)(aptr));
    float4 rA = *(const float4*)(aptr + 64);    // x(1)  (odd steps)
    float4 rB = *(const float4*)(aptr + 128);   // x(2)  (even steps)
    loadB(bfA, 0);
    __syncthreads();

    #pragma unroll
    for (int ks = 0; ks < 16; ks++) {
        const int cur = ks & 1;
        // (1) x refill for step ks+3 (earliest issue -> longest flight time)
        float4 nv;
        const bool doX = (ks + 3 < 16);
        if (doX) nv = *(const float4*)(aptr + (ks + 3) * 64);
        // (2) B prefetch for step ks+1 into the buffer freed at step ks-1
        if (ks + 1 < 16) { if (cur) loadB(bfA, ks + 1); else loadB(bfB, ks + 1); }
        // (3) A-frags from LDS
        short8 af[2][2];
        #pragma unroll
        for (int mf = 0; mf < 2; mf++) {
            int row = (mf << 4) + l16;
            #pragma unroll
            for (int kf = 0; kf < 2; kf++)
                af[mf][kf] = *(const short8*)(&Al[cur][row][((((kf << 2) + lg) ^ (row & 7)) << 3)]);
        }
        // (4) stage x(ks+1) into the other LDS buffer (value loaded 2 steps ago)
        if (ks < 15) writeA(cur ^ 1, ((ks + 1) & 1) ? rA : rB);
        if (doX) { if ((ks + 3) & 1) rA = nv; else rB = nv; }
        // (5) MFMA on current (pre-drained) B regs
        short8 (&bfC)[3][2] = cur ? bfB : bfA;
        #pragma unroll
        for (int kf = 0; kf < 2; kf++)
            #pragma unroll
            for (int mf = 0; mf < 2; mf++)
                #pragma unroll
                for (int nf = 0; nf < 3; nf++)
                    acc[mf][nf] = __builtin_amdgcn_mfma_f32_16x16x32_bf16(af[mf][kf], bfC[nf][kf], acc[mf][nf], 0, 0, 0);
        __syncthreads();
    }

    const float SQ = 0.08838834764831845f * 1.4426950408889634f;  // 1/sqrt(128)*log2e
    unsigned short* Qo = qkv;
    unsigned short* Kp = qkv + (size_t)B_ * T_ * D_;
    unsigned short* Vq = qkv + 2 * (size_t)B_ * T_ * D_;
    #pragma unroll
    for (int mf = 0; mf < 2; mf++) {
        #pragma unroll
        for (int nf = 0; nf < 3; nf++) {
            int cg  = wc + (nf << 4);
            int mat = cg >> 7;
            int cc  = (cg & 127) + l16;
            #pragma unroll
            for (int r = 0; r < 4; r++) {
                int row = m0 + (mf << 4) + (lg << 2) + r;
                float v = acc[mf][nf][r];
                int t = row & (T_ - 1), bb = row >> 12;
                size_t bo = (size_t)bb << 19;
                if (mat == 0) {
                    Qo[(size_t)row * D_ + cc] = f2b(v * SQ);
                } else if (mat == 1) {
                    Kp[bo + ((size_t)(t >> 5) << 12) + ((size_t)(cc >> 4) << 9)
                       + (((cc >> 3) & 1) << 8) + ((t & 31) << 3) + (cc & 7)] = f2b(v);
                } else {
                    int tl = t & 31;
                    Vq[bo + ((size_t)(t >> 5) << 12)
                       + ((size_t)(((tl >> 4) << 2) + (cc >> 5)) << 9)
                       + ((((tl >> 3) & 1) << 8) + ((cc & 31) << 3)) + (tl & 7)] = f2b(v);
                }
            }
        }
    }
}

// ---------------------------------------------------------------------------
// Kernel B: causal flash attention. 512 blocks x 512 thr. (unchanged)
// One 32-row q-tile per block; blocks beta and beta+256 take complementary
// tiles {p, 127-p}. bf16 RAW-partial merge scratch: LDS 66KB -> 2 blocks/CU;
// natural VGPR ~128 -> 4 waves/SIMD. K-loop: 8-way interleaved key split,
// zero barriers, dense 1KB panel loads, in-register softmax (tree + shfl),
// defer-max, in-reg P->A-frag pack (cndmask+shfl). Reader-side merge.
// ---------------------------------------------------------------------------
__global__ __launch_bounds__(512, 2) void attn_fwd(
    const unsigned short* __restrict__ Q,
    const unsigned short* __restrict__ Kp,
    const unsigned short* __restrict__ Vq,
    float* __restrict__ out)
{
    __shared__ unsigned short scb[8][32][128];   // bf16 RAW partials (64KB)
    __shared__ float mlS[8][32][2];

    const int beta0 = blockIdx.x;
    const int sel   = beta0 >> 8;          // 0: tile p, 1: tile 127-p
    const int beta  = beta0 & 255;
    const int xcd   = beta & 7;
    const int b     = xcd >> 1;
    const int pp    = ((beta >> 3) << 1) | (xcd & 1);   // 0..63
    const int it    = sel ? (127 - pp) : pp;
    const int qb    = it << 5;

    const int tid = threadIdx.x, lane = tid & 63, w = tid >> 6;
    const int l32 = lane & 31, lh = lane >> 5;
    const bool lo = (lh == 0);
    const size_t base = (size_t)b * T_ * D_;
    const unsigned short* Kpb = Kp + ((size_t)b << 19);
    const unsigned short* Vqb = Vq + ((size_t)b << 19);

    // Q B-fragments (scale+log2e folded): qf[ds] = Q[qb+l32][16ds+8lh+j]
    short8 qf[8];
    {
        const unsigned short* qp = Q + base + (size_t)(qb + l32) * D_ + (lh << 3);
        #pragma unroll
        for (int ds = 0; ds < 8; ds++) qf[ds] = *(const short8*)(qp + (ds << 4));
    }
    f32x16 accO[4] = {};
    float m_s = -1e30f, l_s = 0.f;

    short8 ka[8], vb[8];

    auto loadKA = [&](int cc) {
        const unsigned short* kp = Kpb + ((size_t)cc << 12) + (lane << 3);
        #pragma unroll
        for (int i = 0; i < 8; i++) ka[i] = *(const short8*)(kp + (i << 9));
    };
    auto loadVB = [&](int cc) {
        const unsigned short* vp = Vqb + ((size_t)cc << 12) + (lane << 3);
        #pragma unroll
        for (int i = 0; i < 8; i++) vb[i] = *(const short8*)(vp + (i << 9));
    };
    auto qkt = [&]() -> f32x16 {
        f32x16 s = {};
        #pragma unroll
        for (int ds = 0; ds < 8; ds++)
            s = __builtin_amdgcn_mfma_f32_32x32x16_bf16(ka[ds], qf[ds], s, 0, 0, 0);
        return s;
    };
    // softmax + pack + PV for chunk cc whose scores are in s2
    auto process = [&](f32x16 &s2, int cc) {
        if (cc == it) {   // diagonal causal mask
            #pragma unroll
            for (int r = 0; r < 16; r++) {
                int kl = (r & 3) + ((r >> 2) << 3) + (lh << 2);
                if (kl > l32) s2[r] = -1e30f;
            }
        }
        // tree max (depth 4) + cross-half shfl
        float t0 = fmaxf(s2[0], s2[1]),   t1 = fmaxf(s2[2], s2[3]);
        float t2 = fmaxf(s2[4], s2[5]),   t3 = fmaxf(s2[6], s2[7]);
        float t4 = fmaxf(s2[8], s2[9]),   t5 = fmaxf(s2[10], s2[11]);
        float t6 = fmaxf(s2[12], s2[13]), t7 = fmaxf(s2[14], s2[15]);
        t0 = fmaxf(t0, t1); t2 = fmaxf(t2, t3); t4 = fmaxf(t4, t5); t6 = fmaxf(t6, t7);
        float mx = fmaxf(fmaxf(t0, t2), fmaxf(t4, t6));
        mx = fmaxf(mx, __shfl_xor(mx, 32));
        // defer-max rescale (rare)
        if (!__all(mx <= m_s + 8.0f)) {
            float mnew = fmaxf(m_s, mx);
            float al = exp2fast(m_s - mnew);
            m_s = mnew; l_s *= al;
            #pragma unroll
            for (int r = 0; r < 16; r++) {
                float av = __shfl(al, (r & 3) + ((r >> 2) << 3) + (lh << 2));
                accO[0][r] *= av; accO[1][r] *= av; accO[2][r] *= av; accO[3][r] *= av;
            }
        }
        #pragma unroll
        for (int r = 0; r < 16; r++) s2[r] = exp2fast(s2[r] - m_s);
        // tree sum + cross-half shfl
        float u0 = s2[0] + s2[1],   u1 = s2[2] + s2[3];
        float u2 = s2[4] + s2[5],   u3 = s2[6] + s2[7];
        float u4 = s2[8] + s2[9],   u5 = s2[10] + s2[11];
        float u6 = s2[12] + s2[13], u7 = s2[14] + s2[15];
        u0 += u1; u2 += u3; u4 += u5; u6 += u7;
        float rs = (u0 + u2) + (u4 + u6);
        rs += __shfl_xor(rs, 32);
        l_s += rs;
        // pack P -> PV A-frags (verified cndmask + shfl transpose)
        unsigned int A0 = pkbf(s2[0],  s2[1]),  B0 = pkbf(s2[2],  s2[3]);
        unsigned int C0 = pkbf(s2[4],  s2[5]),  D0 = pkbf(s2[6],  s2[7]);
        unsigned int A1 = pkbf(s2[8],  s2[9]),  B1 = pkbf(s2[10], s2[11]);
        unsigned int C1 = pkbf(s2[12], s2[13]), D1 = pkbf(s2[14], s2[15]);
        union { unsigned int u[4]; short8 s; } f0, f1;
        {
            unsigned int u0v = lo ? C0 : A0, v0v = lo ? D0 : B0;
            unsigned int su = (unsigned int)__shfl_xor((int)u0v, 32);
            unsigned int sv = (unsigned int)__shfl_xor((int)v0v, 32);
            f0.u[0] = lo ? A0 : su; f0.u[1] = lo ? B0 : sv;
            f0.u[2] = lo ? su : C0; f0.u[3] = lo ? sv : D0;
        }
        {
            unsigned int u1v = lo ? C1 : A1, v1v = lo ? D1 : B1;
            unsigned int su = (unsigned int)__shfl_xor((int)u1v, 32);
            unsigned int sv = (unsigned int)__shfl_xor((int)v1v, 32);
            f1.u[0] = lo ? A1 : su; f1.u[1] = lo ? B1 : sv;
            f1.u[2] = lo ? su : C1; f1.u[3] = lo ? sv : D1;
        }
        // O += P V
        #pragma unroll
        for (int db = 0; db < 4; db++)
            accO[db] = __builtin_amdgcn_mfma_f32_32x32x16_bf16(f0.s, vb[db], accO[db], 0, 0, 0);
        #pragma unroll
        for (int db = 0; db < 4; db++)
            accO[db] = __builtin_amdgcn_mfma_f32_32x32x16_bf16(f1.s, vb[4 + db], accO[db], 0, 0, 0);
    };

    int c = w;
    if (c <= it) {
        loadKA(c);
        loadVB(c);
        #pragma unroll 1
        while (true) {
            f32x16 s2 = qkt();
            bool hn = (c + 8 <= it);
            if (hn) loadKA(c + 8);      // ka free after QK^T
            process(s2, c);
            if (hn) loadVB(c + 8);      // vb free after PV
            c += 8;
            if (!hn) break;
        }
    }

    // ---- 8-way merge: RAW bf16 partials; all per-q weights in the reader ----
    if (lane < 32) { mlS[w][lane][0] = m_s; mlS[w][lane][1] = l_s; }
    #pragma unroll
    for (int r = 0; r < 16; r++) {
        int q = (r & 3) + ((r >> 2) << 3) + (lh << 2);
        #pragma unroll
        for (int db = 0; db < 4; db++)
            scb[w][q][(db << 5) + l32] = f2b(accO[db][r]);
    }
    __syncthreads();
    {
        const int q = tid >> 4, dc = (tid & 15) << 3;
        float fw[8], mst = -1e30f, lst = 0.f;
        #pragma unroll
        for (int w2 = 0; w2 < 8; w2++) mst = fmaxf(mst, mlS[w2][q][0]);
        #pragma unroll
        for (int w2 = 0; w2 < 8; w2++) {
            fw[w2] = exp2fast(mlS[w2][q][0] - mst);
            lst += fw[w2] * mlS[w2][q][1];
        }
        float inv = 1.0f / lst;
        float o[8] = {};
        #pragma unroll
        for (int w2 = 0; w2 < 8; w2++) {
            short8 sv = *(const short8*)(&scb[w2][q][dc]);
            #pragma unroll
            for (int j = 0; j < 8; j++)
                o[j] += fw[w2] * b2f((unsigned short)sv[j]);
        }
        float* op = out + base + (size_t)(qb + q) * D_ + dc;
        f32x4 o0 = { o[0], o[1], o[2], o[3] };
        f32x4 o1 = { o[4], o[5], o[6], o[7] };
        *(f32x4*)op = o0 * inv;
        *(f32x4*)(op + 4) = o1 * inv;
    }
}

extern "C" void kernel_launch(void* const* d_in, const int* in_sizes, int n_in,
                              void* d_out, int out_size, void* d_ws, size_t ws_size,
                              hipStream_t stream) {
    (void)in_sizes; (void)n_in; (void)out_size; (void)ws_size;
    const float* x  = (const float*)d_in[0];
    const float* Wq = (const float*)d_in[1];
    const float* Wk = (const float*)d_in[2];
    const float* Wv = (const float*)d_in[3];

    unsigned short* qkv = (unsigned short*)d_ws;     // Q | Kp | Vq, bf16, 4MB each
    unsigned short* Wp  = (unsigned short*)d_out;    // temp bf16 W panels (overwritten by attn)

    wcvt<<<dim3(192), 256, 0, stream>>>(Wq, Wk, Wv, Wp);
    qkv_gemm<<<dim3(512), 512, 0, stream>>>(x, Wp, qkv);

    const unsigned short* Qw = qkv;
    const unsigned short* Kw = qkv + (size_t)B_ * T_ * D_;
    const unsigned short* Vw = qkv + 2 * (size_t)B_ * T_ * D_;
    attn_fwd<<<dim3(512), 512, 0, stream>>>(Qw, Kw, Vw, (float*)d_out);
}